// Round 1
// baseline (71780.383 us; speedup 1.0000x reference)
//
#include <hip/hip_runtime.h>
#include <hip/hip_bf16.h>
#include <cstdint>

#define BB 256
#define TT 2048
#define KK 64
#define HH 256
#define GG 1024
#define NPRED 512

// ws layout (bytes):
//   WT0  bf16 [320][1024]  @ 0        (655360 B)   packed [k][j][q], row = q*256+j
//   WT1  bf16 [512][1024]  @ 655360   (1048576 B)
//   bias0 f32 [1024]       @ 1703936  (4096 B)     [j*4+q] = b_ih0[row]+b_hh0[row]
//   bias1 f32 [1024]       @ 1708032  (4096 B)
#define WT0_OFF   0
#define WT1_OFF   655360
#define B0_OFF    1703936
#define B1_OFF    1708032

static __device__ __forceinline__ float bf2f(unsigned short u) {
    union { unsigned int i; float f; } v;
    v.i = ((unsigned int)u) << 16;
    return v.f;
}

static __device__ __forceinline__ unsigned short f2bf(float x) {
    __hip_bfloat16 h = __float2bfloat16(x);
    return *reinterpret_cast<unsigned short*>(&h);
}

static __device__ __forceinline__ float sigmoidf_(float x) {
    return 1.0f / (1.0f + __expf(-x));
}

__global__ __launch_bounds__(256) void prep_kernel(
    const float* __restrict__ W_ih0, const float* __restrict__ W_hh0,
    const float* __restrict__ b_ih0, const float* __restrict__ b_hh0,
    const float* __restrict__ W_ih1, const float* __restrict__ W_hh1,
    const float* __restrict__ b_ih1, const float* __restrict__ b_hh1,
    unsigned short* __restrict__ WT0, unsigned short* __restrict__ WT1,
    float* __restrict__ bias0, float* __restrict__ bias1)
{
    int idx = blockIdx.x * 256 + threadIdx.x;
    const int N0 = 320 * 1024;
    const int N1 = 512 * 1024;
    if (idx < N0) {
        int k = idx >> 10, r = idx & 1023;
        int j = r >> 2, q = r & 3, row = q * 256 + j;
        float v = (k < 64) ? W_ih0[row * 64 + k] : W_hh0[row * 256 + (k - 64)];
        WT0[idx] = f2bf(v);
    } else if (idx < N0 + N1) {
        int i2 = idx - N0;
        int k = i2 >> 10, r = i2 & 1023;
        int j = r >> 2, q = r & 3, row = q * 256 + j;
        float v = (k < 256) ? W_ih1[row * 256 + k] : W_hh1[row * 256 + (k - 256)];
        WT1[i2] = f2bf(v);
    } else if (idx < N0 + N1 + 1024) {
        int r = idx - (N0 + N1);
        int j = r >> 2, q = r & 3, row = q * 256 + j;
        bias0[r] = b_ih0[row] + b_hh0[row];
    } else if (idx < N0 + N1 + 2048) {
        int r = idx - (N0 + N1 + 1024);
        int j = r >> 2, q = r & 3, row = q * 256 + j;
        bias1[r] = b_ih1[row] + b_hh1[row];
    }
}

__global__ __launch_bounds__(256) void lstm_scan_kernel(
    const float* __restrict__ input,
    const float* __restrict__ conv_w, const float* __restrict__ conv_b,
    const unsigned short* __restrict__ WT0, const unsigned short* __restrict__ WT1,
    const float* __restrict__ bias0, const float* __restrict__ bias1,
    const float* __restrict__ lin_w, const float* __restrict__ lin_b,
    float* __restrict__ out)
{
    const int b = blockIdx.x;
    const int j = threadIdx.x;

    __shared__ float x_lds[64];
    __shared__ float h0_lds[256];
    __shared__ float h1_lds[256];
    __shared__ float cw[64], cb[64];
    __shared__ float lw[256];
    __shared__ float red[4];
    __shared__ float p_lds;

    if (j < 64) { cw[j] = conv_w[j]; cb[j] = conv_b[j]; }
    lw[j] = lin_w[j];
    h0_lds[j] = 0.0f;
    h1_lds[j] = 0.0f;

    float c0 = 0.0f, c1 = 0.0f;
    float last = 0.0f;
    const float linb = lin_b[0];

    const float4 bs0 = *reinterpret_cast<const float4*>(bias0 + 4 * j);
    const float4 bs1 = *reinterpret_cast<const float4*>(bias1 + 4 * j);
    const float* inp = input + (size_t)b * TT;
    const unsigned short* w0base = WT0 + 4 * j;
    const unsigned short* w1base = WT1 + 4 * j;
    float* outb = out + (size_t)b * NPRED;

    __syncthreads();

    const int NSTEP = TT + NPRED - 1;  // 2559
    for (int step = 0; step < NSTEP; ++step) {
        __syncthreads();  // S0: prev-iter h1 write / p broadcast visible
        if (j < 64) {
            float xv;
            if (step < TT) {
                int f = step * 64 + j;
                xv = inp[f & (TT - 1)] * cw[f >> 11] + cb[f >> 11];
            } else {
                xv = last * cw[j] + cb[j];
            }
            x_lds[j] = fmaxf(xv, 0.0f);
        }
        __syncthreads();  // S1: x ready

        // ---- layer 0: gates = [x | h0] . WT0col(j) + bias ----
        float ai = bs0.x, af = bs0.y, ag = bs0.z, ao = bs0.w;
        #pragma unroll 8
        for (int k = 0; k < 64; ++k) {
            float xv = x_lds[k];
            ushort4 w = *reinterpret_cast<const ushort4*>(w0base + (k << 10));
            ai = fmaf(xv, bf2f(w.x), ai);
            af = fmaf(xv, bf2f(w.y), af);
            ag = fmaf(xv, bf2f(w.z), ag);
            ao = fmaf(xv, bf2f(w.w), ao);
        }
        #pragma unroll 8
        for (int k = 0; k < 256; ++k) {
            float hv = h0_lds[k];
            ushort4 w = *reinterpret_cast<const ushort4*>(w0base + ((64 + k) << 10));
            ai = fmaf(hv, bf2f(w.x), ai);
            af = fmaf(hv, bf2f(w.y), af);
            ag = fmaf(hv, bf2f(w.z), ag);
            ao = fmaf(hv, bf2f(w.w), ao);
        }
        float c0n = sigmoidf_(af) * c0 + sigmoidf_(ai) * tanhf(ag);
        float h0n = sigmoidf_(ao) * tanhf(c0n);
        c0 = c0n;
        __syncthreads();  // S2: everyone done reading old h0
        h0_lds[j] = h0n;
        __syncthreads();  // S3: new h0 ready

        // ---- layer 1: gates = [h0 | h1] . WT1col(j) + bias ----
        ai = bs1.x; af = bs1.y; ag = bs1.z; ao = bs1.w;
        #pragma unroll 8
        for (int k = 0; k < 256; ++k) {
            float hv = h0_lds[k];
            ushort4 w = *reinterpret_cast<const ushort4*>(w1base + (k << 10));
            ai = fmaf(hv, bf2f(w.x), ai);
            af = fmaf(hv, bf2f(w.y), af);
            ag = fmaf(hv, bf2f(w.z), ag);
            ao = fmaf(hv, bf2f(w.w), ao);
        }
        #pragma unroll 8
        for (int k = 0; k < 256; ++k) {
            float hv = h1_lds[k];
            ushort4 w = *reinterpret_cast<const ushort4*>(w1base + ((256 + k) << 10));
            ai = fmaf(hv, bf2f(w.x), ai);
            af = fmaf(hv, bf2f(w.y), af);
            ag = fmaf(hv, bf2f(w.z), ag);
            ao = fmaf(hv, bf2f(w.w), ao);
        }
        float c1n = sigmoidf_(af) * c1 + sigmoidf_(ai) * tanhf(ag);
        float h1n = sigmoidf_(ao) * tanhf(c1n);
        c1 = c1n;
        __syncthreads();  // S4: everyone done reading old h1
        h1_lds[j] = h1n;

        if (step >= TT - 1) {
            // prediction p = h1 . lin_w + lin_b  (block reduction)
            float v = h1n * lw[j];
            v += __shfl_down(v, 32);
            v += __shfl_down(v, 16);
            v += __shfl_down(v, 8);
            v += __shfl_down(v, 4);
            v += __shfl_down(v, 2);
            v += __shfl_down(v, 1);
            if ((j & 63) == 0) red[j >> 6] = v;
            __syncthreads();  // S5
            if (j == 0) {
                float p = red[0] + red[1] + red[2] + red[3] + linb;
                outb[step - (TT - 1)] = p;
                p_lds = p;
            }
            __syncthreads();  // S6
            last = p_lds;
        }
    }
}

extern "C" void kernel_launch(void* const* d_in, const int* in_sizes, int n_in,
                              void* d_out, int out_size, void* d_ws, size_t ws_size,
                              hipStream_t stream) {
    const float* input  = (const float*)d_in[0];
    const float* conv_w = (const float*)d_in[1];
    const float* conv_b = (const float*)d_in[2];
    const float* W_ih0  = (const float*)d_in[3];
    const float* W_hh0  = (const float*)d_in[4];
    const float* b_ih0  = (const float*)d_in[5];
    const float* b_hh0  = (const float*)d_in[6];
    const float* W_ih1  = (const float*)d_in[7];
    const float* W_hh1  = (const float*)d_in[8];
    const float* b_ih1  = (const float*)d_in[9];
    const float* b_hh1  = (const float*)d_in[10];
    const float* lin_w  = (const float*)d_in[11];
    const float* lin_b  = (const float*)d_in[12];
    float* out = (float*)d_out;

    uint8_t* ws = (uint8_t*)d_ws;
    unsigned short* WT0 = (unsigned short*)(ws + WT0_OFF);
    unsigned short* WT1 = (unsigned short*)(ws + WT1_OFF);
    float* bias0 = (float*)(ws + B0_OFF);
    float* bias1 = (float*)(ws + B1_OFF);

    // 320*1024 + 512*1024 + 2048 = 854016 elements -> 3336 blocks of 256
    prep_kernel<<<3336, 256, 0, stream>>>(W_ih0, W_hh0, b_ih0, b_hh0,
                                          W_ih1, W_hh1, b_ih1, b_hh1,
                                          WT0, WT1, bias0, bias1);

    lstm_scan_kernel<<<BB, 256, 0, stream>>>(input, conv_w, conv_b,
                                             WT0, WT1, bias0, bias1,
                                             lin_w, lin_b, out);
}

// Round 2
// 36447.778 us; speedup vs baseline: 1.9694x; 1.9694x over previous
//
#include <hip/hip_runtime.h>
#include <hip/hip_bf16.h>
#include <cstdint>

#define BB 256
#define TT 2048
#define KK 64
#define HH 256
#define NPRED 512

// ws layout (bytes):
//   WQ0  bf16 [160][256][8] @ 0        (655360 B)  pair-packed: (k2,j,e): e&3=gate, e>>2=row-in-pair, k=2*k2+(e>>2)
//   WQ1  bf16 [256][256][8] @ 655360   (1048576 B)
//   bias0 f32 [1024]        @ 1703936  (4096 B)    [j*4+g] = b_ih0[g*256+j]+b_hh0[g*256+j]
//   bias1 f32 [1024]        @ 1708032  (4096 B)
#define WQ0_OFF   0
#define WQ1_OFF   655360
#define B0_OFF    1703936
#define B1_OFF    1708032

static __device__ __forceinline__ unsigned short f2bf(float x) {
    __hip_bfloat16 h = __float2bfloat16(x);
    return *reinterpret_cast<unsigned short*>(&h);
}

static __device__ __forceinline__ float lo16(unsigned int u) {
    union { unsigned int i; float f; } v; v.i = u << 16; return v.f;
}
static __device__ __forceinline__ float hi16(unsigned int u) {
    union { unsigned int i; float f; } v; v.i = u & 0xffff0000u; return v.f;
}

static __device__ __forceinline__ float sigmoidf_(float x) {
    return 1.0f / (1.0f + __expf(-x));
}

__global__ __launch_bounds__(256) void prep_kernel(
    const float* __restrict__ W_ih0, const float* __restrict__ W_hh0,
    const float* __restrict__ b_ih0, const float* __restrict__ b_hh0,
    const float* __restrict__ W_ih1, const float* __restrict__ W_hh1,
    const float* __restrict__ b_ih1, const float* __restrict__ b_hh1,
    unsigned short* __restrict__ WQ0, unsigned short* __restrict__ WQ1,
    float* __restrict__ bias0, float* __restrict__ bias1)
{
    int idx = blockIdx.x * 256 + threadIdx.x;
    const int N0 = 160 * 256 * 8;   // 327680
    const int N1 = 256 * 256 * 8;   // 524288
    if (idx < N0) {
        int k2 = idx >> 11, r = idx & 2047;
        int j = r >> 3, e = r & 7;
        int kk = 2 * k2 + (e >> 2), g = e & 3, row = g * 256 + j;
        float v = (kk < 64) ? W_ih0[row * 64 + kk] : W_hh0[row * 256 + (kk - 64)];
        WQ0[idx] = f2bf(v);
    } else if (idx < N0 + N1) {
        int i2 = idx - N0;
        int k2 = i2 >> 11, r = i2 & 2047;
        int j = r >> 3, e = r & 7;
        int kk = 2 * k2 + (e >> 2), g = e & 3, row = g * 256 + j;
        float v = (kk < 256) ? W_ih1[row * 256 + kk] : W_hh1[row * 256 + (kk - 256)];
        WQ1[i2] = f2bf(v);
    } else if (idx < N0 + N1 + 1024) {
        int r = idx - (N0 + N1);
        int j = r >> 2, g = r & 3, row = g * 256 + j;
        bias0[r] = b_ih0[row] + b_hh0[row];
    } else if (idx < N0 + N1 + 2048) {
        int r = idx - (N0 + N1 + 1024);
        int j = r >> 2, g = r & 3, row = g * 256 + j;
        bias1[r] = b_ih1[row] + b_hh1[row];
    }
}

__global__ __launch_bounds__(1024) void lstm_scan_kernel(
    const float* __restrict__ input,
    const float* __restrict__ conv_w, const float* __restrict__ conv_b,
    const unsigned short* __restrict__ WQ0, const unsigned short* __restrict__ WQ1,
    const float* __restrict__ bias0, const float* __restrict__ bias1,
    const float* __restrict__ lin_w, const float* __restrict__ lin_b,
    float* __restrict__ out)
{
    const int b = blockIdx.x;
    const int t = threadIdx.x;
    const int j = t & 255;   // gate-quad (h index)
    const int q = t >> 8;    // k-slice 0..3

    __shared__ __align__(16) float xh0[320];   // [0..63]=x(t), [64..319]=h0(t-1)
    __shared__ __align__(16) float xh1[512];   // [0..255]=h0(t), [256..511]=h1(t-1)
    __shared__ __align__(16) float part[4][1024];
    __shared__ float cw[64], cb[64], lw[256];
    __shared__ float red[4];
    __shared__ float p_lds;

    if (t < 64)  { cw[t] = conv_w[t]; cb[t] = conv_b[t]; }
    if (t < 256) { lw[t] = lin_w[t]; xh1[t] = 0.0f; xh1[256 + t] = 0.0f; }
    if (t >= 64 && t < 320) xh0[t] = 0.0f;

    float c0 = 0.0f, c1 = 0.0f;
    float last = 0.0f;
    float h1n = 0.0f;
    const float linb = lin_b[0];

    float4 bs0 = make_float4(0.f, 0.f, 0.f, 0.f);
    float4 bs1 = make_float4(0.f, 0.f, 0.f, 0.f);
    if (t < 256) {
        bs0 = *reinterpret_cast<const float4*>(bias0 + 4 * t);
        bs1 = *reinterpret_cast<const float4*>(bias1 + 4 * t);
    }

    const float* inp = input + (size_t)b * TT;
    // thread (q,j): layer0 k2-range [q*40, q*40+40), layer1 [q*64, q*64+64)
    const uint4* w0 = reinterpret_cast<const uint4*>(WQ0) + ((size_t)(q * 40) * 256 + j);
    const uint4* w1 = reinterpret_cast<const uint4*>(WQ1) + ((size_t)(q * 64) * 256 + j);
    float* outb = out + (size_t)b * NPRED;

    __syncthreads();

    const int NSTEP = TT + NPRED - 1;  // 2559
    for (int step = 0; step < NSTEP; ++step) {
        if (t < 64) {
            float xv;
            if (step < TT) {
                int f = step * 64 + t;
                xv = inp[f & (TT - 1)] * cw[f >> 11] + cb[f >> 11];
            } else {
                xv = last * cw[t] + cb[t];
            }
            xh0[t] = fmaxf(xv, 0.0f);
        }
        __syncthreads();  // bar1: x ready; prev-iter part reads done

        // ---- layer 0: 40 row-pair iters ----
        {
            float ai = 0.f, af = 0.f, ag = 0.f, ao = 0.f;
            const float2* xp = reinterpret_cast<const float2*>(xh0 + q * 80);
            #pragma unroll 8
            for (int it = 0; it < 40; ++it) {
                float2 xv = xp[it];
                uint4 w = w0[it * 256];
                ai = fmaf(xv.x, lo16(w.x), ai);
                af = fmaf(xv.x, hi16(w.x), af);
                ag = fmaf(xv.x, lo16(w.y), ag);
                ao = fmaf(xv.x, hi16(w.y), ao);
                ai = fmaf(xv.y, lo16(w.z), ai);
                af = fmaf(xv.y, hi16(w.z), af);
                ag = fmaf(xv.y, lo16(w.w), ag);
                ao = fmaf(xv.y, hi16(w.w), ao);
            }
            *reinterpret_cast<float4*>(&part[q][4 * j]) = make_float4(ai, af, ag, ao);
        }
        __syncthreads();  // bar2: layer-0 partials ready; xh0 h0-region reads done

        if (t < 256) {
            float4 p0 = *reinterpret_cast<const float4*>(&part[0][4 * t]);
            float4 p1 = *reinterpret_cast<const float4*>(&part[1][4 * t]);
            float4 p2 = *reinterpret_cast<const float4*>(&part[2][4 * t]);
            float4 p3 = *reinterpret_cast<const float4*>(&part[3][4 * t]);
            float gi = p0.x + p1.x + p2.x + p3.x + bs0.x;
            float gf = p0.y + p1.y + p2.y + p3.y + bs0.y;
            float gg = p0.z + p1.z + p2.z + p3.z + bs0.z;
            float go = p0.w + p1.w + p2.w + p3.w + bs0.w;
            float c0n = sigmoidf_(gf) * c0 + sigmoidf_(gi) * tanhf(gg);
            float h0n = sigmoidf_(go) * tanhf(c0n);
            c0 = c0n;
            xh0[64 + t] = h0n;   // h0 for next step's layer 0
            xh1[t]      = h0n;   // h0 for this step's layer 1
        }
        __syncthreads();  // bar3: h0 ready; part free for layer 1

        // ---- layer 1: 64 row-pair iters ----
        {
            float ai = 0.f, af = 0.f, ag = 0.f, ao = 0.f;
            const float2* xp = reinterpret_cast<const float2*>(xh1 + q * 128);
            #pragma unroll 8
            for (int it = 0; it < 64; ++it) {
                float2 xv = xp[it];
                uint4 w = w1[it * 256];
                ai = fmaf(xv.x, lo16(w.x), ai);
                af = fmaf(xv.x, hi16(w.x), af);
                ag = fmaf(xv.x, lo16(w.y), ag);
                ao = fmaf(xv.x, hi16(w.y), ao);
                ai = fmaf(xv.y, lo16(w.z), ai);
                af = fmaf(xv.y, hi16(w.z), af);
                ag = fmaf(xv.y, lo16(w.w), ag);
                ao = fmaf(xv.y, hi16(w.w), ao);
            }
            *reinterpret_cast<float4*>(&part[q][4 * j]) = make_float4(ai, af, ag, ao);
        }
        __syncthreads();  // bar4: layer-1 partials ready; xh1 reads done

        if (t < 256) {
            float4 p0 = *reinterpret_cast<const float4*>(&part[0][4 * t]);
            float4 p1 = *reinterpret_cast<const float4*>(&part[1][4 * t]);
            float4 p2 = *reinterpret_cast<const float4*>(&part[2][4 * t]);
            float4 p3 = *reinterpret_cast<const float4*>(&part[3][4 * t]);
            float gi = p0.x + p1.x + p2.x + p3.x + bs1.x;
            float gf = p0.y + p1.y + p2.y + p3.y + bs1.y;
            float gg = p0.z + p1.z + p2.z + p3.z + bs1.z;
            float go = p0.w + p1.w + p2.w + p3.w + bs1.w;
            float c1n = sigmoidf_(gf) * c1 + sigmoidf_(gi) * tanhf(gg);
            h1n = sigmoidf_(go) * tanhf(c1n);
            c1 = c1n;
            xh1[256 + t] = h1n;
        }

        if (step >= TT - 1) {
            float v = (t < 256) ? h1n * lw[t] : 0.0f;
            v += __shfl_down(v, 32);
            v += __shfl_down(v, 16);
            v += __shfl_down(v, 8);
            v += __shfl_down(v, 4);
            v += __shfl_down(v, 2);
            v += __shfl_down(v, 1);
            if (t < 256 && (t & 63) == 0) red[t >> 6] = v;
            __syncthreads();  // barP1
            if (t == 0) {
                float p = red[0] + red[1] + red[2] + red[3] + linb;
                outb[step - (TT - 1)] = p;
                p_lds = p;
            }
            __syncthreads();  // barP2: p broadcast
            last = p_lds;
        }
    }
}

extern "C" void kernel_launch(void* const* d_in, const int* in_sizes, int n_in,
                              void* d_out, int out_size, void* d_ws, size_t ws_size,
                              hipStream_t stream) {
    const float* input  = (const float*)d_in[0];
    const float* conv_w = (const float*)d_in[1];
    const float* conv_b = (const float*)d_in[2];
    const float* W_ih0  = (const float*)d_in[3];
    const float* W_hh0  = (const float*)d_in[4];
    const float* b_ih0  = (const float*)d_in[5];
    const float* b_hh0  = (const float*)d_in[6];
    const float* W_ih1  = (const float*)d_in[7];
    const float* W_hh1  = (const float*)d_in[8];
    const float* b_ih1  = (const float*)d_in[9];
    const float* b_hh1  = (const float*)d_in[10];
    const float* lin_w  = (const float*)d_in[11];
    const float* lin_b  = (const float*)d_in[12];
    float* out = (float*)d_out;

    uint8_t* ws = (uint8_t*)d_ws;
    unsigned short* WQ0 = (unsigned short*)(ws + WQ0_OFF);
    unsigned short* WQ1 = (unsigned short*)(ws + WQ1_OFF);
    float* bias0 = (float*)(ws + B0_OFF);
    float* bias1 = (float*)(ws + B1_OFF);

    // 327680 + 524288 + 2048 = 854016 elements -> 3336 blocks of 256
    prep_kernel<<<3336, 256, 0, stream>>>(W_ih0, W_hh0, b_ih0, b_hh0,
                                          W_ih1, W_hh1, b_ih1, b_hh1,
                                          WQ0, WQ1, bias0, bias1);

    lstm_scan_kernel<<<BB, 1024, 0, stream>>>(input, conv_w, conv_b,
                                              WQ0, WQ1, bias0, bias1,
                                              lin_w, lin_b, out);
}

// Round 3
// 29858.289 us; speedup vs baseline: 2.4040x; 1.2207x over previous
//
#include <hip/hip_runtime.h>
#include <hip/hip_bf16.h>
#include <cstdint>

#define BB 256
#define TT 2048
#define NPRED 512

// ws layout (bytes):
#define WQ0_OFF  0u          // bf16 [160][256][8]  655360
#define WQ1_OFF  655360u     // bf16 [256][256][8]  1048576
#define B0_OFF   1703936u    // f32 [1024]          4096
#define B1_OFF   1708032u    // f32 [1024]          4096
#define WH1_OFF  1712128u    // bf16 [128][256][8]  524288   (W_hh1 pair-packed)
#define WI1_OFF  2236416u    // bf16 [1024][256]    524288   (W_ih1 plain)
#define H0F_OFF  2760704u    // f32 [256][256]      262144
#define C0F_OFF  3022848u
#define H1F_OFF  3284992u
#define C1F_OFF  3547136u
#define HB_OFF   3809280u    // h0c bf16 [256][Tc][256]; G1 f32 follows

typedef __attribute__((ext_vector_type(8))) short bf16x8;
typedef __attribute__((ext_vector_type(4))) float f32x4;

static __device__ __forceinline__ unsigned short f2bf(float x) {
    __hip_bfloat16 h = __float2bfloat16(x);
    return *reinterpret_cast<unsigned short*>(&h);
}
static __device__ __forceinline__ float lo16(unsigned int u) {
    union { unsigned int i; float f; } v; v.i = u << 16; return v.f;
}
static __device__ __forceinline__ float hi16(unsigned int u) {
    union { unsigned int i; float f; } v; v.i = u & 0xffff0000u; return v.f;
}
static __device__ __forceinline__ float sigmoidf_(float x) {
    return 1.0f / (1.0f + __expf(-x));
}

// ---------------- prep: repack weights ----------------
__global__ __launch_bounds__(256) void prep_kernel(
    const float* __restrict__ W_ih0, const float* __restrict__ W_hh0,
    const float* __restrict__ b_ih0, const float* __restrict__ b_hh0,
    const float* __restrict__ W_ih1, const float* __restrict__ W_hh1,
    const float* __restrict__ b_ih1, const float* __restrict__ b_hh1,
    unsigned short* __restrict__ WQ0, unsigned short* __restrict__ WQ1,
    float* __restrict__ bias0, float* __restrict__ bias1,
    unsigned short* __restrict__ WH1, unsigned short* __restrict__ WI1,
    int full)
{
    int idx = blockIdx.x * 256 + threadIdx.x;
    const int N0 = 160 * 256 * 8;   // 327680
    const int N1 = 256 * 256 * 8;   // 524288
    if (idx < N0) {
        int k2 = idx >> 11, r = idx & 2047;
        int j = r >> 3, e = r & 7;
        int kk = 2 * k2 + (e >> 2), g = e & 3, row = g * 256 + j;
        float v = (kk < 64) ? W_ih0[row * 64 + kk] : W_hh0[row * 256 + (kk - 64)];
        WQ0[idx] = f2bf(v);
    } else if (idx < N0 + N1) {
        int i2 = idx - N0;
        int k2 = i2 >> 11, r = i2 & 2047;
        int j = r >> 3, e = r & 7;
        int kk = 2 * k2 + (e >> 2), g = e & 3, row = g * 256 + j;
        float v = (kk < 256) ? W_ih1[row * 256 + kk] : W_hh1[row * 256 + (kk - 256)];
        WQ1[i2] = f2bf(v);
    } else if (idx < N0 + N1 + 1024) {
        int r = idx - (N0 + N1);
        int j = r >> 2, g = r & 3, row = g * 256 + j;
        bias0[r] = b_ih0[row] + b_hh0[row];
    } else if (idx < N0 + N1 + 2048) {
        int r = idx - (N0 + N1 + 1024);
        int j = r >> 2, g = r & 3, row = g * 256 + j;
        bias1[r] = b_ih1[row] + b_hh1[row];
    } else if (full && idx < N0 + N1 + 2048 + 262144) {
        int i3 = idx - (N0 + N1 + 2048);
        int k2 = i3 >> 11, r = i3 & 2047;
        int j = r >> 3, e = r & 7;
        int kk = 2 * k2 + (e >> 2), g = e & 3, row = g * 256 + j;
        WH1[i3] = f2bf(W_hh1[row * 256 + kk]);
    } else if (full && idx < N0 + N1 + 2048 + 524288) {
        int i4 = idx - (N0 + N1 + 2048 + 262144);
        WI1[i4] = f2bf(W_ih1[i4]);
    }
}

// ---------------- scan0: layer-0 only, writes h0 sequence ----------------
__global__ __launch_bounds__(1024) void scan0_kernel(
    const float* __restrict__ input,
    const float* __restrict__ conv_w, const float* __restrict__ conv_b,
    const unsigned short* __restrict__ WQ0, const float* __restrict__ bias0,
    unsigned short* __restrict__ h0c,
    float* __restrict__ h0f, float* __restrict__ c0f,
    int chunk, int Tc)
{
    const int b = blockIdx.x;
    const int t = threadIdx.x;
    const int j = t & 255, q = t >> 8;
    __shared__ __align__(16) float xh0[320];
    __shared__ __align__(16) float part[4][1024];
    __shared__ float cw[64], cb[64];

    if (t < 64) { cw[t] = conv_w[t]; cb[t] = conv_b[t]; }
    float c0 = 0.f;
    float4 bs0 = make_float4(0.f, 0.f, 0.f, 0.f);
    if (t < 256) {
        bs0 = *reinterpret_cast<const float4*>(bias0 + 4 * t);
        xh0[64 + t] = (chunk == 0) ? 0.f : h0f[b * 256 + t];
        c0 = (chunk == 0) ? 0.f : c0f[b * 256 + t];
    }
    const float* inp = input + (size_t)b * TT;
    const uint4* w0 = reinterpret_cast<const uint4*>(WQ0) + ((size_t)(q * 40) * 256 + j);
    unsigned short* hb = h0c + (size_t)b * Tc * 256;
    __syncthreads();

    float h0n = 0.f;
    for (int tl = 0; tl < Tc; ++tl) {
        int st = chunk * Tc + tl;
        if (t < 64) {
            int f = st * 64 + t;
            xh0[t] = fmaxf(inp[f & (TT - 1)] * cw[f >> 11] + cb[f >> 11], 0.f);
        }
        __syncthreads();
        {
            float ai = 0.f, af = 0.f, ag = 0.f, ao = 0.f;
            const float2* xp = reinterpret_cast<const float2*>(xh0 + q * 80);
            #pragma unroll 8
            for (int it = 0; it < 40; ++it) {
                float2 xv = xp[it];
                uint4 w = w0[it * 256];
                ai = fmaf(xv.x, lo16(w.x), ai);
                af = fmaf(xv.x, hi16(w.x), af);
                ag = fmaf(xv.x, lo16(w.y), ag);
                ao = fmaf(xv.x, hi16(w.y), ao);
                ai = fmaf(xv.y, lo16(w.z), ai);
                af = fmaf(xv.y, hi16(w.z), af);
                ag = fmaf(xv.y, lo16(w.w), ag);
                ao = fmaf(xv.y, hi16(w.w), ao);
            }
            *reinterpret_cast<float4*>(&part[q][4 * j]) = make_float4(ai, af, ag, ao);
        }
        __syncthreads();
        if (t < 256) {
            float4 p0 = *reinterpret_cast<const float4*>(&part[0][4 * t]);
            float4 p1 = *reinterpret_cast<const float4*>(&part[1][4 * t]);
            float4 p2 = *reinterpret_cast<const float4*>(&part[2][4 * t]);
            float4 p3 = *reinterpret_cast<const float4*>(&part[3][4 * t]);
            float gi = p0.x + p1.x + p2.x + p3.x + bs0.x;
            float gf = p0.y + p1.y + p2.y + p3.y + bs0.y;
            float gg = p0.z + p1.z + p2.z + p3.z + bs0.z;
            float go = p0.w + p1.w + p2.w + p3.w + bs0.w;
            float c0n = sigmoidf_(gf) * c0 + sigmoidf_(gi) * tanhf(gg);
            h0n = sigmoidf_(go) * tanhf(c0n);
            c0 = c0n;
            xh0[64 + t] = h0n;
            hb[(size_t)tl * 256 + t] = f2bf(h0n);
        }
        __syncthreads();
    }
    if (t < 256) { h0f[b * 256 + t] = h0n; c0f[b * 256 + t] = c0; }
}

// ---------------- gemm: G1 = h0c @ W_ih1^T  (MFMA bf16) ----------------
__global__ __launch_bounds__(256) void gemm_ih1_kernel(
    const unsigned short* __restrict__ A,   // [M][256] bf16
    const unsigned short* __restrict__ Bw,  // [1024][256] bf16
    float* __restrict__ C)                  // [M][1024] f32
{
    __shared__ unsigned short As[128 * 64];
    __shared__ unsigned short Bs[128 * 64];
    const int tid = threadIdx.x;
    const int bm = blockIdx.x >> 3, bn = blockIdx.x & 7;
    const int lane = tid & 63, w = tid >> 6;
    const int wm = w >> 1, wn = w & 1;

    f32x4 acc[4][4] = {};
    for (int kt = 0; kt < 4; ++kt) {
        #pragma unroll
        for (int i = 0; i < 4; ++i) {
            int g = tid + i * 256;
            int r = g >> 3, gg = g & 7;
            uint4 va = *reinterpret_cast<const uint4*>(A + (size_t)(bm * 128 + r) * 256 + kt * 64 + gg * 8);
            uint4 vb = *reinterpret_cast<const uint4*>(Bw + (size_t)(bn * 128 + r) * 256 + kt * 64 + gg * 8);
            int dst = r * 128 + ((gg ^ (r & 7)) << 4);
            *reinterpret_cast<uint4*>((char*)As + dst) = va;
            *reinterpret_cast<uint4*>((char*)Bs + dst) = vb;
        }
        __syncthreads();
        #pragma unroll
        for (int kh = 0; kh < 2; ++kh) {
            bf16x8 av[4], bv[4];
            #pragma unroll
            for (int fm = 0; fm < 4; ++fm) {
                int r = wm * 64 + fm * 16 + (lane & 15);
                int gk = (lane >> 4) + kh * 4;
                av[fm] = *reinterpret_cast<const bf16x8*>((char*)As + r * 128 + ((gk ^ (r & 7)) << 4));
            }
            #pragma unroll
            for (int fn = 0; fn < 4; ++fn) {
                int r = wn * 64 + fn * 16 + (lane & 15);
                int gk = (lane >> 4) + kh * 4;
                bv[fn] = *reinterpret_cast<const bf16x8*>((char*)Bs + r * 128 + ((gk ^ (r & 7)) << 4));
            }
            #pragma unroll
            for (int fm = 0; fm < 4; ++fm)
                #pragma unroll
                for (int fn = 0; fn < 4; ++fn)
                    acc[fm][fn] = __builtin_amdgcn_mfma_f32_16x16x32_bf16(av[fm], bv[fn], acc[fm][fn], 0, 0, 0);
        }
        __syncthreads();
    }
    #pragma unroll
    for (int fm = 0; fm < 4; ++fm) {
        int m0 = bm * 128 + wm * 64 + fm * 16 + (lane >> 4) * 4;
        #pragma unroll
        for (int fn = 0; fn < 4; ++fn) {
            int n = bn * 128 + wn * 64 + fn * 16 + (lane & 15);
            #pragma unroll
            for (int r = 0; r < 4; ++r)
                C[(size_t)(m0 + r) * 1024 + n] = acc[fm][fn][r];
        }
    }
}

// ---------------- scan1: layer-1 only, consumes G1 ----------------
__global__ __launch_bounds__(1024) void scan1_kernel(
    const unsigned short* __restrict__ WH1, const float* __restrict__ bias1,
    const float* __restrict__ G1,
    float* __restrict__ h1f, float* __restrict__ c1f,
    int chunk, int Tc)
{
    const int b = blockIdx.x;
    const int t = threadIdx.x;
    const int j = t & 255, q = t >> 8;
    __shared__ __align__(16) float hbuf[256];
    __shared__ __align__(16) float part[4][1024];

    float c1 = 0.f;
    float4 bs1 = make_float4(0.f, 0.f, 0.f, 0.f);
    if (t < 256) {
        bs1 = *reinterpret_cast<const float4*>(bias1 + 4 * t);
        hbuf[t] = (chunk == 0) ? 0.f : h1f[b * 256 + t];
        c1 = (chunk == 0) ? 0.f : c1f[b * 256 + t];
    }
    const uint4* w1 = reinterpret_cast<const uint4*>(WH1) + ((size_t)(q * 32) * 256 + j);
    const float* Gb = G1 + (size_t)b * Tc * 1024;
    __syncthreads();

    float h1n = 0.f;
    for (int tl = 0; tl < Tc; ++tl) {
        {
            float ai = 0.f, af = 0.f, ag = 0.f, ao = 0.f;
            const float2* xp = reinterpret_cast<const float2*>(hbuf + q * 64);
            #pragma unroll 8
            for (int it = 0; it < 32; ++it) {
                float2 xv = xp[it];
                uint4 w = w1[it * 256];
                ai = fmaf(xv.x, lo16(w.x), ai);
                af = fmaf(xv.x, hi16(w.x), af);
                ag = fmaf(xv.x, lo16(w.y), ag);
                ao = fmaf(xv.x, hi16(w.y), ao);
                ai = fmaf(xv.y, lo16(w.z), ai);
                af = fmaf(xv.y, hi16(w.z), af);
                ag = fmaf(xv.y, lo16(w.w), ag);
                ao = fmaf(xv.y, hi16(w.w), ao);
            }
            *reinterpret_cast<float4*>(&part[q][4 * j]) = make_float4(ai, af, ag, ao);
        }
        __syncthreads();
        if (t < 256) {
            float4 p0 = *reinterpret_cast<const float4*>(&part[0][4 * t]);
            float4 p1 = *reinterpret_cast<const float4*>(&part[1][4 * t]);
            float4 p2 = *reinterpret_cast<const float4*>(&part[2][4 * t]);
            float4 p3 = *reinterpret_cast<const float4*>(&part[3][4 * t]);
            const float* gp = Gb + (size_t)tl * 1024 + t;
            float gi = p0.x + p1.x + p2.x + p3.x + bs1.x + gp[0];
            float gf = p0.y + p1.y + p2.y + p3.y + bs1.y + gp[256];
            float gg = p0.z + p1.z + p2.z + p3.z + bs1.z + gp[512];
            float go = p0.w + p1.w + p2.w + p3.w + bs1.w + gp[768];
            float c1n = sigmoidf_(gf) * c1 + sigmoidf_(gi) * tanhf(gg);
            h1n = sigmoidf_(go) * tanhf(c1n);
            c1 = c1n;
            hbuf[t] = h1n;
        }
        __syncthreads();
    }
    if (t < 256) { h1f[b * 256 + t] = h1n; c1f[b * 256 + t] = c1; }
}

// ---------------- AR: 511 autoregressive steps + pred0 ----------------
__global__ __launch_bounds__(1024) void ar_kernel(
    const float* __restrict__ conv_w, const float* __restrict__ conv_b,
    const unsigned short* __restrict__ WQ0, const unsigned short* __restrict__ WQ1,
    const float* __restrict__ bias0, const float* __restrict__ bias1,
    const float* __restrict__ lin_w, const float* __restrict__ lin_b,
    const float* __restrict__ h0f, const float* __restrict__ c0f,
    const float* __restrict__ h1f, const float* __restrict__ c1f,
    float* __restrict__ out)
{
    const int b = blockIdx.x;
    const int t = threadIdx.x;
    const int j = t & 255, q = t >> 8;

    __shared__ __align__(16) float xh0[320];
    __shared__ __align__(16) float xh1[512];
    __shared__ __align__(16) float part[4][1024];
    __shared__ float cw[64], cb[64], lw[256];
    __shared__ float red[4];
    __shared__ float p_lds;

    if (t < 64) { cw[t] = conv_w[t]; cb[t] = conv_b[t]; }
    float c0 = 0.f, c1 = 0.f, h1n = 0.f;
    const float linb = lin_b[0];
    float4 bs0 = make_float4(0.f, 0.f, 0.f, 0.f);
    float4 bs1 = make_float4(0.f, 0.f, 0.f, 0.f);
    if (t < 256) {
        lw[t] = lin_w[t];
        bs0 = *reinterpret_cast<const float4*>(bias0 + 4 * t);
        bs1 = *reinterpret_cast<const float4*>(bias1 + 4 * t);
        xh0[64 + t] = h0f[b * 256 + t];
        c0 = c0f[b * 256 + t];
        h1n = h1f[b * 256 + t];
        xh1[256 + t] = h1n;
        xh1[t] = 0.f;
        c1 = c1f[b * 256 + t];
    }
    const uint4* w0 = reinterpret_cast<const uint4*>(WQ0) + ((size_t)(q * 40) * 256 + j);
    const uint4* w1 = reinterpret_cast<const uint4*>(WQ1) + ((size_t)(q * 64) * 256 + j);
    float* outb = out + (size_t)b * NPRED;
    __syncthreads();

    // pred0 from final scan state
    float last;
    {
        float v = (t < 256) ? h1n * lw[t] : 0.f;
        v += __shfl_down(v, 32); v += __shfl_down(v, 16); v += __shfl_down(v, 8);
        v += __shfl_down(v, 4);  v += __shfl_down(v, 2);  v += __shfl_down(v, 1);
        if (t < 256 && (t & 63) == 0) red[t >> 6] = v;
        __syncthreads();
        if (t == 0) {
            float p = red[0] + red[1] + red[2] + red[3] + linb;
            outb[0] = p;
            p_lds = p;
        }
        __syncthreads();
        last = p_lds;
    }

    for (int i = 0; i < NPRED - 1; ++i) {
        if (t < 64) xh0[t] = fmaxf(last * cw[t] + cb[t], 0.f);
        __syncthreads();
        {
            float ai = 0.f, af = 0.f, ag = 0.f, ao = 0.f;
            const float2* xp = reinterpret_cast<const float2*>(xh0 + q * 80);
            #pragma unroll 8
            for (int it = 0; it < 40; ++it) {
                float2 xv = xp[it];
                uint4 w = w0[it * 256];
                ai = fmaf(xv.x, lo16(w.x), ai);
                af = fmaf(xv.x, hi16(w.x), af);
                ag = fmaf(xv.x, lo16(w.y), ag);
                ao = fmaf(xv.x, hi16(w.y), ao);
                ai = fmaf(xv.y, lo16(w.z), ai);
                af = fmaf(xv.y, hi16(w.z), af);
                ag = fmaf(xv.y, lo16(w.w), ag);
                ao = fmaf(xv.y, hi16(w.w), ao);
            }
            *reinterpret_cast<float4*>(&part[q][4 * j]) = make_float4(ai, af, ag, ao);
        }
        __syncthreads();
        if (t < 256) {
            float4 p0 = *reinterpret_cast<const float4*>(&part[0][4 * t]);
            float4 p1 = *reinterpret_cast<const float4*>(&part[1][4 * t]);
            float4 p2 = *reinterpret_cast<const float4*>(&part[2][4 * t]);
            float4 p3 = *reinterpret_cast<const float4*>(&part[3][4 * t]);
            float gi = p0.x + p1.x + p2.x + p3.x + bs0.x;
            float gf = p0.y + p1.y + p2.y + p3.y + bs0.y;
            float gg = p0.z + p1.z + p2.z + p3.z + bs0.z;
            float go = p0.w + p1.w + p2.w + p3.w + bs0.w;
            float c0n = sigmoidf_(gf) * c0 + sigmoidf_(gi) * tanhf(gg);
            float h0n = sigmoidf_(go) * tanhf(c0n);
            c0 = c0n;
            xh0[64 + t] = h0n;
            xh1[t] = h0n;
        }
        __syncthreads();
        {
            float ai = 0.f, af = 0.f, ag = 0.f, ao = 0.f;
            const float2* xp = reinterpret_cast<const float2*>(xh1 + q * 128);
            #pragma unroll 8
            for (int it = 0; it < 64; ++it) {
                float2 xv = xp[it];
                uint4 w = w1[it * 256];
                ai = fmaf(xv.x, lo16(w.x), ai);
                af = fmaf(xv.x, hi16(w.x), af);
                ag = fmaf(xv.x, lo16(w.y), ag);
                ao = fmaf(xv.x, hi16(w.y), ao);
                ai = fmaf(xv.y, lo16(w.z), ai);
                af = fmaf(xv.y, hi16(w.z), af);
                ag = fmaf(xv.y, lo16(w.w), ag);
                ao = fmaf(xv.y, hi16(w.w), ao);
            }
            *reinterpret_cast<float4*>(&part[q][4 * j]) = make_float4(ai, af, ag, ao);
        }
        __syncthreads();
        if (t < 256) {
            float4 p0 = *reinterpret_cast<const float4*>(&part[0][4 * t]);
            float4 p1 = *reinterpret_cast<const float4*>(&part[1][4 * t]);
            float4 p2 = *reinterpret_cast<const float4*>(&part[2][4 * t]);
            float4 p3 = *reinterpret_cast<const float4*>(&part[3][4 * t]);
            float gi = p0.x + p1.x + p2.x + p3.x + bs1.x;
            float gf = p0.y + p1.y + p2.y + p3.y + bs1.y;
            float gg = p0.z + p1.z + p2.z + p3.z + bs1.z;
            float go = p0.w + p1.w + p2.w + p3.w + bs1.w;
            float c1n = sigmoidf_(gf) * c1 + sigmoidf_(gi) * tanhf(gg);
            h1n = sigmoidf_(go) * tanhf(c1n);
            c1 = c1n;
            xh1[256 + t] = h1n;
        }
        {
            float v = (t < 256) ? h1n * lw[t] : 0.f;
            v += __shfl_down(v, 32); v += __shfl_down(v, 16); v += __shfl_down(v, 8);
            v += __shfl_down(v, 4);  v += __shfl_down(v, 2);  v += __shfl_down(v, 1);
            if (t < 256 && (t & 63) == 0) red[t >> 6] = v;
        }
        __syncthreads();
        if (t == 0) {
            float p = red[0] + red[1] + red[2] + red[3] + linb;
            outb[1 + i] = p;
            p_lds = p;
        }
        __syncthreads();
        last = p_lds;
    }
}

// ---------------- monolith fallback (R1 kernel, used only if ws too small) ----------------
__global__ __launch_bounds__(1024) void mono_kernel(
    const float* __restrict__ input,
    const float* __restrict__ conv_w, const float* __restrict__ conv_b,
    const unsigned short* __restrict__ WQ0, const unsigned short* __restrict__ WQ1,
    const float* __restrict__ bias0, const float* __restrict__ bias1,
    const float* __restrict__ lin_w, const float* __restrict__ lin_b,
    float* __restrict__ out)
{
    const int b = blockIdx.x;
    const int t = threadIdx.x;
    const int j = t & 255, q = t >> 8;
    __shared__ __align__(16) float xh0[320];
    __shared__ __align__(16) float xh1[512];
    __shared__ __align__(16) float part[4][1024];
    __shared__ float cw[64], cb[64], lw[256];
    __shared__ float red[4];
    __shared__ float p_lds;

    if (t < 64)  { cw[t] = conv_w[t]; cb[t] = conv_b[t]; }
    if (t < 256) { lw[t] = lin_w[t]; xh1[t] = 0.0f; xh1[256 + t] = 0.0f; }
    if (t >= 64 && t < 320) xh0[t] = 0.0f;
    float c0 = 0.f, c1 = 0.f, last = 0.f, h1n = 0.f;
    const float linb = lin_b[0];
    float4 bs0 = make_float4(0.f,0.f,0.f,0.f), bs1 = make_float4(0.f,0.f,0.f,0.f);
    if (t < 256) {
        bs0 = *reinterpret_cast<const float4*>(bias0 + 4 * t);
        bs1 = *reinterpret_cast<const float4*>(bias1 + 4 * t);
    }
    const float* inp = input + (size_t)b * TT;
    const uint4* w0 = reinterpret_cast<const uint4*>(WQ0) + ((size_t)(q * 40) * 256 + j);
    const uint4* w1 = reinterpret_cast<const uint4*>(WQ1) + ((size_t)(q * 64) * 256 + j);
    float* outb = out + (size_t)b * NPRED;
    __syncthreads();
    const int NSTEP = TT + NPRED - 1;
    for (int step = 0; step < NSTEP; ++step) {
        if (t < 64) {
            float xv;
            if (step < TT) {
                int f = step * 64 + t;
                xv = inp[f & (TT - 1)] * cw[f >> 11] + cb[f >> 11];
            } else xv = last * cw[t] + cb[t];
            xh0[t] = fmaxf(xv, 0.0f);
        }
        __syncthreads();
        {
            float ai = 0.f, af = 0.f, ag = 0.f, ao = 0.f;
            const float2* xp = reinterpret_cast<const float2*>(xh0 + q * 80);
            #pragma unroll 8
            for (int it = 0; it < 40; ++it) {
                float2 xv = xp[it]; uint4 w = w0[it * 256];
                ai = fmaf(xv.x, lo16(w.x), ai); af = fmaf(xv.x, hi16(w.x), af);
                ag = fmaf(xv.x, lo16(w.y), ag); ao = fmaf(xv.x, hi16(w.y), ao);
                ai = fmaf(xv.y, lo16(w.z), ai); af = fmaf(xv.y, hi16(w.z), af);
                ag = fmaf(xv.y, lo16(w.w), ag); ao = fmaf(xv.y, hi16(w.w), ao);
            }
            *reinterpret_cast<float4*>(&part[q][4 * j]) = make_float4(ai, af, ag, ao);
        }
        __syncthreads();
        if (t < 256) {
            float4 p0 = *reinterpret_cast<const float4*>(&part[0][4 * t]);
            float4 p1 = *reinterpret_cast<const float4*>(&part[1][4 * t]);
            float4 p2 = *reinterpret_cast<const float4*>(&part[2][4 * t]);
            float4 p3 = *reinterpret_cast<const float4*>(&part[3][4 * t]);
            float gi = p0.x+p1.x+p2.x+p3.x+bs0.x, gf = p0.y+p1.y+p2.y+p3.y+bs0.y;
            float gg = p0.z+p1.z+p2.z+p3.z+bs0.z, go = p0.w+p1.w+p2.w+p3.w+bs0.w;
            float c0n = sigmoidf_(gf) * c0 + sigmoidf_(gi) * tanhf(gg);
            float h0n = sigmoidf_(go) * tanhf(c0n);
            c0 = c0n; xh0[64 + t] = h0n; xh1[t] = h0n;
        }
        __syncthreads();
        {
            float ai = 0.f, af = 0.f, ag = 0.f, ao = 0.f;
            const float2* xp = reinterpret_cast<const float2*>(xh1 + q * 128);
            #pragma unroll 8
            for (int it = 0; it < 64; ++it) {
                float2 xv = xp[it]; uint4 w = w1[it * 256];
                ai = fmaf(xv.x, lo16(w.x), ai); af = fmaf(xv.x, hi16(w.x), af);
                ag = fmaf(xv.x, lo16(w.y), ag); ao = fmaf(xv.x, hi16(w.y), ao);
                ai = fmaf(xv.y, lo16(w.z), ai); af = fmaf(xv.y, hi16(w.z), af);
                ag = fmaf(xv.y, lo16(w.w), ag); ao = fmaf(xv.y, hi16(w.w), ao);
            }
            *reinterpret_cast<float4*>(&part[q][4 * j]) = make_float4(ai, af, ag, ao);
        }
        __syncthreads();
        if (t < 256) {
            float4 p0 = *reinterpret_cast<const float4*>(&part[0][4 * t]);
            float4 p1 = *reinterpret_cast<const float4*>(&part[1][4 * t]);
            float4 p2 = *reinterpret_cast<const float4*>(&part[2][4 * t]);
            float4 p3 = *reinterpret_cast<const float4*>(&part[3][4 * t]);
            float gi = p0.x+p1.x+p2.x+p3.x+bs1.x, gf = p0.y+p1.y+p2.y+p3.y+bs1.y;
            float gg = p0.z+p1.z+p2.z+p3.z+bs1.z, go = p0.w+p1.w+p2.w+p3.w+bs1.w;
            float c1n = sigmoidf_(gf) * c1 + sigmoidf_(gi) * tanhf(gg);
            h1n = sigmoidf_(go) * tanhf(c1n);
            c1 = c1n; xh1[256 + t] = h1n;
        }
        if (step >= TT - 1) {
            float v = (t < 256) ? h1n * lw[t] : 0.0f;
            v += __shfl_down(v, 32); v += __shfl_down(v, 16); v += __shfl_down(v, 8);
            v += __shfl_down(v, 4);  v += __shfl_down(v, 2);  v += __shfl_down(v, 1);
            if (t < 256 && (t & 63) == 0) red[t >> 6] = v;
            __syncthreads();
            if (t == 0) {
                float p = red[0] + red[1] + red[2] + red[3] + linb;
                outb[step - (TT - 1)] = p; p_lds = p;
            }
            __syncthreads();
            last = p_lds;
        }
    }
}

extern "C" void kernel_launch(void* const* d_in, const int* in_sizes, int n_in,
                              void* d_out, int out_size, void* d_ws, size_t ws_size,
                              hipStream_t stream) {
    const float* input  = (const float*)d_in[0];
    const float* conv_w = (const float*)d_in[1];
    const float* conv_b = (const float*)d_in[2];
    const float* W_ih0  = (const float*)d_in[3];
    const float* W_hh0  = (const float*)d_in[4];
    const float* b_ih0  = (const float*)d_in[5];
    const float* b_hh0  = (const float*)d_in[6];
    const float* W_ih1  = (const float*)d_in[7];
    const float* W_hh1  = (const float*)d_in[8];
    const float* b_ih1  = (const float*)d_in[9];
    const float* b_hh1  = (const float*)d_in[10];
    const float* lin_w  = (const float*)d_in[11];
    const float* lin_b  = (const float*)d_in[12];
    float* out = (float*)d_out;

    uint8_t* ws = (uint8_t*)d_ws;
    unsigned short* WQ0 = (unsigned short*)(ws + WQ0_OFF);
    unsigned short* WQ1 = (unsigned short*)(ws + WQ1_OFF);
    float* bias0 = (float*)(ws + B0_OFF);
    float* bias1 = (float*)(ws + B1_OFF);
    unsigned short* WH1 = (unsigned short*)(ws + WH1_OFF);
    unsigned short* WI1 = (unsigned short*)(ws + WI1_OFF);
    float* h0f = (float*)(ws + H0F_OFF);
    float* c0f = (float*)(ws + C0F_OFF);
    float* h1f = (float*)(ws + H1F_OFF);
    float* c1f = (float*)(ws + C1F_OFF);

    // pick Tc (chunk length): h0c = Tc*131072 B, G1 = Tc*1048576 B
    int Tc = 0;
    for (int cand = 128; cand >= 8; cand >>= 1) {
        if ((size_t)HB_OFF + (size_t)cand * (131072u + 1048576u) <= ws_size) { Tc = cand; break; }
    }

    if (Tc == 0) {
        // tiny workspace fallback: monolithic R1 path
        prep_kernel<<<3336, 256, 0, stream>>>(W_ih0, W_hh0, b_ih0, b_hh0,
                                              W_ih1, W_hh1, b_ih1, b_hh1,
                                              WQ0, WQ1, bias0, bias1, WH1, WI1, 0);
        mono_kernel<<<BB, 1024, 0, stream>>>(input, conv_w, conv_b, WQ0, WQ1,
                                             bias0, bias1, lin_w, lin_b, out);
        return;
    }

    unsigned short* h0c = (unsigned short*)(ws + HB_OFF);
    float* G1 = (float*)(ws + HB_OFF + (size_t)Tc * 131072u);

    prep_kernel<<<5384, 256, 0, stream>>>(W_ih0, W_hh0, b_ih0, b_hh0,
                                          W_ih1, W_hh1, b_ih1, b_hh1,
                                          WQ0, WQ1, bias0, bias1, WH1, WI1, 1);

    const int chunks = TT / Tc;
    const int gemm_grid = (2 * Tc) * 8;   // Mtiles * Ntiles
    for (int c = 0; c < chunks; ++c) {
        scan0_kernel<<<BB, 1024, 0, stream>>>(input, conv_w, conv_b, WQ0, bias0,
                                              h0c, h0f, c0f, c, Tc);
        gemm_ih1_kernel<<<gemm_grid, 256, 0, stream>>>(h0c, WI1, G1);
        scan1_kernel<<<BB, 1024, 0, stream>>>(WH1, bias1, G1, h1f, c1f, c, Tc);
    }
    ar_kernel<<<BB, 1024, 0, stream>>>(conv_w, conv_b, WQ0, WQ1, bias0, bias1,
                                       lin_w, lin_b, h0f, c0f, h1f, c1f, out);
}